// Round 15
// baseline (136.297 us; speedup 1.0000x reference)
//
#include <hip/hip_runtime.h>

#define NPTS 16384
#define GS   32
#define NC   (GS * GS * GS)
#define BBOX 4.0f
#define H    0.25f
#define INVH 4.0f
#define RMAX 15
#define TABN 29791                // 31^3 packed shell offsets, ring-sorted
#define QL   16                   // lanes per query

__device__ __forceinline__ int cellco(float v) {
    int c = (int)floorf((v + BBOX) * INVH);
    return min(max(c, 0), GS - 1);
}

// ---- pass 1: per-cell histograms --------------------------------------
__global__ void hist_k(const float* __restrict__ s, const float* __restrict__ t,
                       int* __restrict__ cntS, int* __restrict__ cntT) {
    int i = blockIdx.x * blockDim.x + threadIdx.x;
    int cloud = i >> 14, p = i & (NPTS - 1);
    const float* base = cloud ? t : s;
    float x = base[3 * p], y = base[3 * p + 1], z = base[3 * p + 2];
    int id = (cellco(x) * GS + cellco(y)) * GS + cellco(z);
    atomicAdd((cloud ? cntT : cntS) + id, 1);
}

// ---- pass 2: scan -> rng{start,start} pairs + shell-table gen ----------
__global__ __launch_bounds__(1024)
void scan_k(const int* __restrict__ cntS, const int* __restrict__ cntT,
            int2* __restrict__ rngS, int2* __restrict__ rngT,
            int* __restrict__ tab) {
    __shared__ int2 part[1024];
    __shared__ int ringc[RMAX + 1];
    int t = threadIdx.x;
    if (t <= RMAX) ringc[t] = 0;

    const int4* cS4 = (const int4*)cntS;
    const int4* cT4 = (const int4*)cntT;
    int4 bufS[8], bufT[8];
    int a = 0, b = 0;
#pragma unroll
    for (int k = 0; k < 8; ++k) {
        bufS[k] = cS4[t * 8 + k];
        bufT[k] = cT4[t * 8 + k];
        a += bufS[k].x + bufS[k].y + bufS[k].z + bufS[k].w;
        b += bufT[k].x + bufT[k].y + bufT[k].z + bufT[k].w;
    }
    part[t] = make_int2(a, b);
    __syncthreads();
    for (int off = 1; off < 1024; off <<= 1) {       // Hillis-Steele inclusive
        int2 add = (t >= off) ? part[t - off] : make_int2(0, 0);
        __syncthreads();
        part[t].x += add.x; part[t].y += add.y;
        __syncthreads();
    }
    int2 run = (t > 0) ? part[t - 1] : make_int2(0, 0);
    int4* rS4 = (int4*)rngS;
    int4* rT4 = (int4*)rngT;
#pragma unroll
    for (int k = 0; k < 8; ++k) {
        int s0 = run.x, s1 = s0 + bufS[k].x, s2 = s1 + bufS[k].y, s3 = s2 + bufS[k].z;
        run.x = s3 + bufS[k].w;
        rS4[t * 16 + 2 * k]     = make_int4(s0, s0, s1, s1);
        rS4[t * 16 + 2 * k + 1] = make_int4(s2, s2, s3, s3);
        s0 = run.y; s1 = s0 + bufT[k].x; s2 = s1 + bufT[k].y; s3 = s2 + bufT[k].z;
        run.y = s3 + bufT[k].w;
        rT4[t * 16 + 2 * k]     = make_int4(s0, s0, s1, s1);
        rT4[t * 16 + 2 * k + 1] = make_int4(s2, s2, s3, s3);
    }
    // shell table: offsets in [-15,15]^3 grouped by Chebyshev ring r;
    // ring r occupies tab[(2r-1)^3 .. (2r+1)^3); order within ring arbitrary.
    for (unsigned idx = t; idx < TABN; idx += 1024) {
        unsigned q1 = idx / 961u, rem = idx - q1 * 961u;
        unsigned q2 = rem / 31u,  q3 = rem - q2 * 31u;
        int ring = max(max(abs((int)q1 - 15), abs((int)q2 - 15)), abs((int)q3 - 15));
        int pos = 0;
        if (ring > 0) {
            int w = 2 * ring - 1;
            pos = w * w * w + atomicAdd(&ringc[ring], 1);
        }
        tab[pos] = ((int)q1 << 10) | ((int)q2 << 5) | (int)q3;
    }
}

// ---- pass 3: destructive scatter (rng.y: start -> end) ------------------
__global__ void scatter_k(const float* __restrict__ s, const float* __restrict__ t,
                          int* __restrict__ rngS, int* __restrict__ rngT,
                          float4* __restrict__ sortedS, float4* __restrict__ sortedT) {
    int i = blockIdx.x * blockDim.x + threadIdx.x;
    int cloud = i >> 14, p = i & (NPTS - 1);
    const float* base = cloud ? t : s;
    float x = base[3 * p], y = base[3 * p + 1], z = base[3 * p + 2];
    int id = (cellco(x) * GS + cellco(y)) * GS + cellco(z);
    int pos = atomicAdd((cloud ? rngT : rngS) + 2 * id + 1, 1);
    (cloud ? sortedT : sortedS)[pos] = make_float4(x, y, z, __int_as_float(p));
}

// ---- pass 4: exact NN, 16 lanes/query, 1-wave blocks --------------------
__global__ __launch_bounds__(64)
void query_k(const float4* __restrict__ sortedS, const float4* __restrict__ sortedT,
             const int2* __restrict__ rngS, const int2* __restrict__ rngT,
             const int* __restrict__ tab, float* __restrict__ out) {
    int tid = blockIdx.x * 64 + threadIdx.x;
    int q = tid >> 4, g = tid & (QL - 1);
    int cloud = q >> 14, j = q & (NPTS - 1);
    float4 qp = (cloud ? sortedT : sortedS)[j];      // sorted: coherent groups
    const float4* __restrict__ pts = cloud ? sortedS : sortedT;
    const int2* __restrict__ rng = cloud ? rngS : rngT;

    float qx = qp.x, qy = qp.y, qz = qp.z;
    int cx = cellco(qx), cy = cellco(qy), cz = cellco(qz);
    float minwall = fminf(fminf(fminf(qx - (-BBOX + cx * H), (-BBOX + (cx + 1) * H) - qx),
                                fminf(qy - (-BBOX + cy * H), (-BBOX + (cy + 1) * H) - qy)),
                          fminf(qz - (-BBOX + cz * H), (-BBOX + (cz + 1) * H) - qz));
    minwall = fmaxf(minwall, 0.0f);

    float best = 1e30f;

#define SCAN_CELL(ix, iy, iz)                                                  \
    {                                                                          \
        float clx = -BBOX + (ix) * H, cly = -BBOX + (iy) * H,                  \
              clz = -BBOX + (iz) * H;                                          \
        float dx = fmaxf(0.f, fmaxf((ix) == 0 ? -1.f : clx - qx,               \
                                    (ix) == GS - 1 ? -1.f : qx - clx - H));    \
        float dy = fmaxf(0.f, fmaxf((iy) == 0 ? -1.f : cly - qy,               \
                                    (iy) == GS - 1 ? -1.f : qy - cly - H));    \
        float dz = fmaxf(0.f, fmaxf((iz) == 0 ? -1.f : clz - qz,               \
                                    (iz) == GS - 1 ? -1.f : qz - clz - H));    \
        float lb = fmaf(dx, dx, fmaf(dy, dy, dz * dz));                        \
        if (lb < best) {                                                       \
            int c = ((ix) * GS + (iy)) * GS + (iz);                            \
            int2 v = rng[c];                                                   \
            for (int k = v.x; k < v.y; ++k) {                                  \
                float4 p = pts[k];                                             \
                float ax = qx - p.x, ay = qy - p.y, az = qz - p.z;             \
                best = fminf(best, fmaf(ax, ax, fmaf(ay, ay, az * az)));       \
            }                                                                  \
        }                                                                      \
    }

    for (int r = 0; r < GS; ++r) {
        float bu = best;
        bu = fminf(bu, __shfl_xor(bu, 1, QL));
        bu = fminf(bu, __shfl_xor(bu, 2, QL));
        bu = fminf(bu, __shfl_xor(bu, 4, QL));
        bu = fminf(bu, __shfl_xor(bu, 8, QL));
        if (r >= 1) {
            float lb = minwall + (float)(r - 1) * H;
            if (lb * lb >= bu) break;
        }
        best = bu;

        if (r == 0) {                      // home cell: strided over 16 lanes
            int c = (cx * GS + cy) * GS + cz;
            int2 v = rng[c];
            for (int k = v.x + g; k < v.y; k += QL) {
                float4 p = pts[k];
                float ax = qx - p.x, ay = qy - p.y, az = qz - p.z;
                best = fminf(best, fmaf(ax, ax, fmaf(ay, ay, az * az)));
            }
        } else if (r <= RMAX) {            // table-driven shell (div-free)
            int w = 2 * r - 1, W = 2 * r + 1;
            int i0 = w * w * w, i1 = W * W * W;
            for (int idx = i0 + g; idx < i1; idx += QL) {
                int pk = tab[idx];
                int ix = cx + (pk >> 10) - 15;
                int iy = cy + ((pk >> 5) & 31) - 15;
                int iz = cz + (pk & 31) - 15;
                if ((unsigned)ix >= GS || (unsigned)iy >= GS || (unsigned)iz >= GS)
                    continue;
                SCAN_CELL(ix, iy, iz)
            }
        } else {                           // r>15: needs NN dist > 3.5 — near-impossible
            unsigned W = 2 * r + 1, W2 = W * W, tot = W2 * W;
            for (unsigned idx = g; idx < tot; idx += QL) {
                unsigned q1 = idx / W2, rem = idx - q1 * W2;
                unsigned q2 = rem / W, q3 = rem - q2 * W;
                int dxo = (int)q1 - r, dyo = (int)q2 - r, dzo = (int)q3 - r;
                if (max(max(abs(dxo), abs(dyo)), abs(dzo)) != r) continue;
                int ix = cx + dxo, iy = cy + dyo, iz = cz + dzo;
                if ((unsigned)ix >= GS || (unsigned)iy >= GS || (unsigned)iz >= GS)
                    continue;
                SCAN_CELL(ix, iy, iz)
            }
        }
    }
#undef SCAN_CELL

    float bu = best;
    bu = fminf(bu, __shfl_xor(bu, 1, QL));
    bu = fminf(bu, __shfl_xor(bu, 2, QL));
    bu = fminf(bu, __shfl_xor(bu, 4, QL));
    bu = fminf(bu, __shfl_xor(bu, 8, QL));
    if (g == 0) out[cloud * NPTS + __float_as_int(qp.w)] = bu;
}

extern "C" void kernel_launch(void* const* d_in, const int* in_sizes, int n_in,
                              void* d_out, int out_size, void* d_ws, size_t ws_size,
                              hipStream_t stream) {
    const float* s = (const float*)d_in[0];
    const float* t = (const float*)d_in[1];

    int* wsI = (int*)d_ws;
    int* cntS = wsI;                         // NC
    int* cntT = wsI + NC;                    // NC
    int2* rngS = (int2*)(wsI + 2 * NC);      // NC int2
    int2* rngT = rngS + NC;                  // NC int2
    int* tab = wsI + 6 * NC;                 // 29792 (padded)
    float4* sortedS = (float4*)(wsI + 6 * NC + 29792);   // NPTS
    float4* sortedT = sortedS + NPTS;                    // NPTS

    hipMemsetAsync(cntS, 0, (size_t)2 * NC * sizeof(int), stream);
    hist_k<<<(2 * NPTS) / 256, 256, 0, stream>>>(s, t, cntS, cntT);
    scan_k<<<1, 1024, 0, stream>>>(cntS, cntT, rngS, rngT, tab);
    scatter_k<<<(2 * NPTS) / 256, 256, 0, stream>>>(s, t, (int*)rngS, (int*)rngT,
                                                    sortedS, sortedT);
    query_k<<<(2 * NPTS * QL) / 64, 64, 0, stream>>>(sortedS, sortedT,
                                                     rngS, rngT, tab,
                                                     (float*)d_out);
}